// Round 1
// baseline (133.710 us; speedup 1.0000x reference)
//
#include <hip/hip_runtime.h>

#define L_SEQ 4096
#define D_DIM 512
#define H_DIM 512
#define P_PAD 16

// tanh(v) = 1 - 2/(exp(2v)+1); clamp so exp never overflows. v_exp + v_rcp,
// error ~1e-6 absolute -- far below the 1.78e-2 harness threshold.
__device__ __forceinline__ float fast_tanh(float v) {
    v = fminf(fmaxf(v, -9.0f), 9.0f);
    float e = __expf(2.0f * v);
    return 1.0f - 2.0f * __builtin_amdgcn_rcpf(e + 1.0f);
}

// C[l,h] = sum_d x[l,d] * W[h,d]; W/out selected by blockIdx.z (Ww->wx, Wu->ux).
// 64x64 tile, BK=16, 256 threads, 4x4 microtile per thread.
__global__ __launch_bounds__(256) void dual_gemm_kernel(
    const float* __restrict__ x, const float* __restrict__ Ww,
    const float* __restrict__ Wu, float* __restrict__ wx, float* __restrict__ ux)
{
    const float* W = (blockIdx.z == 0) ? Ww : Wu;
    float*     out = (blockIdx.z == 0) ? wx : ux;
    const int row0 = blockIdx.x * 64;
    const int col0 = blockIdx.y * 64;

    // 68 floats/row: row stride 272 B (16B-aligned) so float4 LDS reads are legal.
    __shared__ __align__(16) float As[16][68];  // As[k][m] = x[row0+m][k0+k]
    __shared__ __align__(16) float Bs[16][68];  // Bs[k][n] = W[col0+n][k0+k]

    const int tid = threadIdx.x;
    const int lr  = tid >> 2;         // 0..63 : row within tile for loading
    const int lk  = (tid & 3) << 2;   // 0,4,8,12 : k offset for loading
    const int tm  = (tid & 15) << 2;  // 0..60 : micro-tile row base
    const int tn  = (tid >> 4) << 2;  // 0..60 : micro-tile col base

    float acc[4][4] = {};

    for (int k0 = 0; k0 < D_DIM; k0 += 16) {
        float4 av = *(const float4*)&x[(row0 + lr) * D_DIM + k0 + lk];
        float4 bv = *(const float4*)&W[(col0 + lr) * D_DIM + k0 + lk];
        As[lk + 0][lr] = av.x; As[lk + 1][lr] = av.y;
        As[lk + 2][lr] = av.z; As[lk + 3][lr] = av.w;
        Bs[lk + 0][lr] = bv.x; Bs[lk + 1][lr] = bv.y;
        Bs[lk + 2][lr] = bv.z; Bs[lk + 3][lr] = bv.w;
        __syncthreads();
        #pragma unroll
        for (int k = 0; k < 16; ++k) {
            float a[4], b[4];
            *(float4*)a = *(const float4*)&As[k][tm];
            *(float4*)b = *(const float4*)&Bs[k][tn];
            #pragma unroll
            for (int i = 0; i < 4; ++i)
                #pragma unroll
                for (int j = 0; j < 4; ++j)
                    acc[i][j] += a[i] * b[j];
        }
        __syncthreads();
    }

    #pragma unroll
    for (int i = 0; i < 4; ++i) {
        float4 v = make_float4(acc[i][0], acc[i][1], acc[i][2], acc[i][3]);
        *(float4*)&out[(row0 + tm + i) * H_DIM + col0 + tn] = v;
    }
}

// One block per sequence position l. 4 waves x 8 window offsets each.
__global__ __launch_bounds__(256) void attn_kernel(
    const float* __restrict__ x, const float* __restrict__ wx,
    const float* __restrict__ ux, const float* __restrict__ Wv,
    float* __restrict__ g)
{
    const int l    = blockIdx.x;
    const int tid  = threadIdx.x;
    const int wave = tid >> 6;
    const int lane = tid & 63;

    __shared__ float wxs[H_DIM];
    __shared__ float wvs[H_DIM];
    __shared__ float scores[2 * P_PAD];
    __shared__ float attn[2 * P_PAD];

    for (int i = tid; i < H_DIM; i += 256) {
        wxs[i] = wx[l * H_DIM + i];
        wvs[i] = Wv[i];
    }
    __syncthreads();

    // scores[w] = sum_h Wv[h] * tanh(wx[l,h] + ux[l+j,h]),  ux row = 0 if OOB
    for (int wi = 0; wi < 8; ++wi) {
        const int w = wave * 8 + wi;                       // 0..31
        const int j = (w < P_PAD) ? (w - P_PAD) : (w - P_PAD + 1); // -16..-1, 1..16
        const int n = l + j;
        float s = 0.0f;
        if (n >= 0 && n < L_SEQ) {
            #pragma unroll
            for (int hh = 0; hh < 8; ++hh) {
                const int h = lane + hh * 64;
                s += wvs[h] * fast_tanh(wxs[h] + ux[n * H_DIM + h]);
            }
        } else {
            #pragma unroll
            for (int hh = 0; hh < 8; ++hh) {
                const int h = lane + hh * 64;
                s += wvs[h] * fast_tanh(wxs[h]);
            }
        }
        #pragma unroll
        for (int off = 32; off; off >>= 1) s += __shfl_xor(s, off);
        if (lane == 0) scores[w] = s;
    }
    __syncthreads();

    // softmax over the 32 window scores (lanes 0..31 of wave 0)
    if (tid < 32) {
        float sc = scores[tid];
        float m = sc;
        #pragma unroll
        for (int off = 16; off; off >>= 1) m = fmaxf(m, __shfl_xor(m, off, 32));
        float e = __expf(sc - m);
        float sum = e;
        #pragma unroll
        for (int off = 16; off; off >>= 1) sum += __shfl_xor(sum, off, 32);
        attn[tid] = e / sum;
    }
    __syncthreads();

    // g[l,d] = sum_w attn[w] * x[l+j_w, d]   (OOB rows contribute 0)
    #pragma unroll
    for (int dd = 0; dd < 2; ++dd) {
        const int d = tid + dd * 256;
        float acc = 0.0f;
        #pragma unroll
        for (int w = 0; w < 2 * P_PAD; ++w) {
            const int j = (w < P_PAD) ? (w - P_PAD) : (w - P_PAD + 1);
            const int n = l + j;
            if (n >= 0 && n < L_SEQ) acc += attn[w] * x[n * D_DIM + d];
        }
        g[l * D_DIM + d] = acc;
    }
}

extern "C" void kernel_launch(void* const* d_in, const int* in_sizes, int n_in,
                              void* d_out, int out_size, void* d_ws, size_t ws_size,
                              hipStream_t stream) {
    const float* x  = (const float*)d_in[0];
    const float* Ww = (const float*)d_in[1];
    const float* Wu = (const float*)d_in[2];
    const float* Wv = (const float*)d_in[3];
    float* g  = (float*)d_out;
    float* wx = (float*)d_ws;                 // [L, H]  8 MB
    float* ux = wx + (size_t)L_SEQ * H_DIM;   // [L, H]  8 MB

    dim3 gemm_grid(L_SEQ / 64, H_DIM / 64, 2);
    dual_gemm_kernel<<<gemm_grid, 256, 0, stream>>>(x, Ww, Wu, wx, ux);
    attn_kernel<<<dim3(L_SEQ), 256, 0, stream>>>(x, wx, ux, Wv, g);
}

// Round 2
// 119.106 us; speedup vs baseline: 1.1226x; 1.1226x over previous
//
#include <hip/hip_runtime.h>

#define L_SEQ 4096
#define D_DIM 512
#define H_DIM 512
#define P_PAD 16
#define LB 4   // l-rows per attn block

typedef __bf16 bf16x8 __attribute__((ext_vector_type(8)));
typedef float  f32x4  __attribute__((ext_vector_type(4)));

__device__ __forceinline__ ushort f2bf(float f) {
    unsigned u = __float_as_uint(f);
    return (ushort)((u + 0x7FFFu + ((u >> 16) & 1u)) >> 16);   // RNE
}

// tanh(t) = 1 - 2/(exp(2t)+1). No clamp needed: exp->inf gives rcp->0 -> 1;
// exp->0 gives -1. ~6 VALU ops via v_exp + v_rcp.
__device__ __forceinline__ float tanh_fast(float t) {
    float e = __expf(2.0f * t);
    float r = __builtin_amdgcn_rcpf(e + 1.0f);
    return __builtin_fmaf(-2.0f, r, 1.0f);
}

// ---- f32 -> bf16 conversion of x, Ww, Wu (float4 granularity) ----
__global__ __launch_bounds__(256) void convert_kernel(
    const float* __restrict__ x, const float* __restrict__ Ww,
    const float* __restrict__ Wu, ushort* __restrict__ xb,
    ushort* __restrict__ Wwb, ushort* __restrict__ Wub)
{
    int i = blockIdx.x * 256 + threadIdx.x;  // float4 index, 0..655359
    const float* src; ushort* dst; int off;
    if (i < 524288)      { src = x;  dst = xb;  off = i; }
    else if (i < 589824) { src = Ww; dst = Wwb; off = i - 524288; }
    else                 { src = Wu; dst = Wub; off = i - 589824; }
    float4 v = ((const float4*)src)[off];
    ushort4 o;
    o.x = f2bf(v.x); o.y = f2bf(v.y); o.z = f2bf(v.z); o.w = f2bf(v.w);
    ((ushort4*)dst)[off] = o;
}

// ---- C[m][n] = sum_k A[m][k]*W[n][k], bf16 MFMA 16x16x32, f32 out ----
// Tile 128(M) x 64(N) x 64(K); 4 waves in 2x2; per wave 64x32 = 4x2 frags.
__global__ __launch_bounds__(256) void dual_gemm_mfma(
    const ushort* __restrict__ xb, const ushort* __restrict__ Wwb,
    const ushort* __restrict__ Wub, float* __restrict__ wx, float* __restrict__ ux)
{
    const ushort* B = blockIdx.z ? Wub : Wwb;
    float*       out = blockIdx.z ? ux : wx;
    const int m0 = blockIdx.x * 128;
    const int n0 = blockIdx.y * 64;

    __shared__ __align__(16) ushort As[128 * 64];  // [m][k] row-major 16KB
    __shared__ __align__(16) ushort Bs[64 * 64];   // [n][k] row-major  8KB

    const int tid  = threadIdx.x;
    const int wv   = tid >> 6;
    const int lane = tid & 63;
    const int wm   = (wv >> 1) * 64;   // wave M offset in tile
    const int wn   = (wv & 1) * 32;    // wave N offset in tile
    const int lr   = lane & 15;        // fragment row/col
    const int lg   = lane >> 4;        // k-group (8 contiguous k per lane)

    f32x4 acc[4][2] = {};

    for (int k0 = 0; k0 < D_DIM; k0 += 64) {
        // stage A tile: 1024 x 16B chunks; chunk c -> row c>>3, k-chunk c&7
        #pragma unroll
        for (int i = 0; i < 4; ++i) {
            int c = i * 256 + tid;
            const ushort* src = xb + (size_t)(m0 + (c >> 3)) * D_DIM + k0 + (c & 7) * 8;
            ushort* dst = As + (i * 256 + wv * 64) * 8;   // wave-uniform base
            __builtin_amdgcn_global_load_lds(
                (const __attribute__((address_space(1))) void*)src,
                (__attribute__((address_space(3))) void*)dst, 16, 0, 0);
        }
        // stage B tile: 512 chunks
        #pragma unroll
        for (int i = 0; i < 2; ++i) {
            int c = i * 256 + tid;
            const ushort* src = B + (size_t)(n0 + (c >> 3)) * D_DIM + k0 + (c & 7) * 8;
            ushort* dst = Bs + (i * 256 + wv * 64) * 8;
            __builtin_amdgcn_global_load_lds(
                (const __attribute__((address_space(1))) void*)src,
                (__attribute__((address_space(3))) void*)dst, 16, 0, 0);
        }
        __syncthreads();

        #pragma unroll
        for (int kk = 0; kk < 2; ++kk) {
            bf16x8 a[4], b[2];
            #pragma unroll
            for (int mi = 0; mi < 4; ++mi)
                a[mi] = *(const bf16x8*)&As[(wm + mi * 16 + lr) * 64 + kk * 32 + lg * 8];
            #pragma unroll
            for (int ni = 0; ni < 2; ++ni)
                b[ni] = *(const bf16x8*)&Bs[(wn + ni * 16 + lr) * 64 + kk * 32 + lg * 8];
            #pragma unroll
            for (int mi = 0; mi < 4; ++mi)
                #pragma unroll
                for (int ni = 0; ni < 2; ++ni)
                    acc[mi][ni] = __builtin_amdgcn_mfma_f32_16x16x32_bf16(
                        a[mi], b[ni], acc[mi][ni], 0, 0, 0);
        }
        __syncthreads();
    }

    // D layout: col = lane&15, row = (lane>>4)*4 + r
    #pragma unroll
    for (int mi = 0; mi < 4; ++mi)
        #pragma unroll
        for (int ni = 0; ni < 2; ++ni)
            #pragma unroll
            for (int r = 0; r < 4; ++r)
                out[(size_t)(m0 + wm + mi * 16 + lg * 4 + r) * H_DIM + n0 + wn + ni * 16 + lr] =
                    acc[mi][ni][r];
}

// ---- fused scores/softmax/gather: LB=4 l's per block, wave per l ----
__global__ __launch_bounds__(256, 4) void attn_kernel(
    const float* __restrict__ x, const float* __restrict__ wx,
    const float* __restrict__ ux, const float* __restrict__ Wv,
    float* __restrict__ g)
{
    // XCD swizzle: grid=1024, 8 XCDs -> 128 consecutive blocks per XCD
    const int bid  = (blockIdx.x & 7) * 128 + (blockIdx.x >> 3);
    const int l0   = bid * LB;
    const int tid  = threadIdx.x;
    const int wave = tid >> 6;
    const int lane = tid & 63;
    const int l    = l0 + wave;

    __shared__ float sc_lds[LB][32];
    __shared__ float at_lds[LB][32];

    // ---- phase 1: scores[l][w] = sum_h Wv[h]*tanh(wx[l,h]+ux[l+j,h]) ----
    float s[32];
    #pragma unroll
    for (int w = 0; w < 32; ++w) s[w] = 0.0f;

    #pragma unroll
    for (int c = 0; c < 2; ++c) {
        const int hb = lane * 4 + c * 256;
        float4 wx4 = *(const float4*)&wx[(size_t)l * H_DIM + hb];
        float4 wv4 = *(const float4*)&Wv[hb];
        #pragma unroll
        for (int w = 0; w < 32; ++w) {
            const int j = (w < P_PAD) ? (w - P_PAD) : (w - P_PAD + 1);
            const int n = l + j;
            float4 u4 = make_float4(0.f, 0.f, 0.f, 0.f);
            if (n >= 0 && n < L_SEQ)
                u4 = *(const float4*)&ux[(size_t)n * H_DIM + hb];
            float t = wv4.x * tanh_fast(wx4.x + u4.x);
            t = __builtin_fmaf(wv4.y, tanh_fast(wx4.y + u4.y), t);
            t = __builtin_fmaf(wv4.z, tanh_fast(wx4.z + u4.z), t);
            t = __builtin_fmaf(wv4.w, tanh_fast(wx4.w + u4.w), t);
            s[w] += t;
        }
    }
    // wave-reduce each of the 32 accumulators; lane w stores window w
    #pragma unroll
    for (int w = 0; w < 32; ++w) {
        float v = s[w];
        #pragma unroll
        for (int off = 32; off; off >>= 1) v += __shfl_xor(v, off);
        if (lane == w) sc_lds[wave][w] = v;
    }
    __syncthreads();

    // ---- phase 2: softmax over 32 windows, one half-wave per l ----
    if (tid < LB * 32) {
        const int ll = tid >> 5, w = tid & 31;
        float sc = sc_lds[ll][w];
        float m = sc;
        #pragma unroll
        for (int off = 16; off; off >>= 1) m = fmaxf(m, __shfl_xor(m, off, 32));
        float e = __expf(sc - m);
        float sum = e;
        #pragma unroll
        for (int off = 16; off; off >>= 1) sum += __shfl_xor(sum, off, 32);
        at_lds[ll][w] = e * __builtin_amdgcn_rcpf(sum);
    }
    __syncthreads();

    // ---- phase 3: g[l][d] = sum_w attn*x[l+j][d]; share 36 x-rows ----
    const int d = tid * 2;
    float2 acc[LB];
    #pragma unroll
    for (int li = 0; li < LB; ++li) acc[li] = make_float2(0.f, 0.f);

    #pragma unroll
    for (int t = 0; t < 36; ++t) {
        const int n = l0 - P_PAD + t;
        if (n >= 0 && n < L_SEQ) {
            float2 xv = *(const float2*)&x[(size_t)n * D_DIM + d];
            #pragma unroll
            for (int li = 0; li < LB; ++li) {
                const int j = t - P_PAD - li;          // compile-time per (t,li)
                if (j >= -P_PAD && j <= P_PAD && j != 0) {
                    const int w = (j < 0) ? j + P_PAD : j + P_PAD - 1;
                    float a = at_lds[li][w];
                    acc[li].x = __builtin_fmaf(a, xv.x, acc[li].x);
                    acc[li].y = __builtin_fmaf(a, xv.y, acc[li].y);
                }
            }
        }
    }
    #pragma unroll
    for (int li = 0; li < LB; ++li)
        *(float2*)&g[(size_t)(l0 + li) * D_DIM + d] = acc[li];
}

extern "C" void kernel_launch(void* const* d_in, const int* in_sizes, int n_in,
                              void* d_out, int out_size, void* d_ws, size_t ws_size,
                              hipStream_t stream) {
    const float* x  = (const float*)d_in[0];
    const float* Ww = (const float*)d_in[1];
    const float* Wu = (const float*)d_in[2];
    const float* Wv = (const float*)d_in[3];
    float* g = (float*)d_out;

    float*  wx  = (float*)d_ws;                          // 8 MB
    float*  ux  = wx + (size_t)L_SEQ * H_DIM;            // 8 MB
    ushort* xb  = (ushort*)(ux + (size_t)L_SEQ * H_DIM); // 4 MB
    ushort* Wwb = xb + (size_t)L_SEQ * D_DIM;            // 0.5 MB
    ushort* Wub = Wwb + (size_t)H_DIM * D_DIM;           // 0.5 MB

    convert_kernel<<<dim3(2560), 256, 0, stream>>>(x, Ww, Wu, xb, Wwb, Wub);
    dual_gemm_mfma<<<dim3(L_SEQ / 128, H_DIM / 64, 2), 256, 0, stream>>>(xb, Wwb, Wub, wx, ux);
    attn_kernel<<<dim3(L_SEQ / LB), 256, 0, stream>>>(x, wx, ux, Wv, g);
}

// Round 3
// 62.984 us; speedup vs baseline: 2.1229x; 1.8910x over previous
//
#include <hip/hip_runtime.h>

#define L_SEQ 4096
#define D_DIM 512
#define H_DIM 512
#define P_PAD 16
#define LB 4                      // l-rows per attn block
#define NROWS (LB + 2 * P_PAD)    // 36 ux rows staged per block

typedef __bf16 bf16x8 __attribute__((ext_vector_type(8)));
typedef float  f32x4  __attribute__((ext_vector_type(4)));
typedef unsigned short u16x8 __attribute__((ext_vector_type(8)));

__device__ __forceinline__ ushort f2bf(float f) {
    unsigned u = __float_as_uint(f);
    return (ushort)((u + 0x7FFFu + ((u >> 16) & 1u)) >> 16);   // RNE
}

// tanh(t) = 1 - 2/(exp(2t)+1); exp->inf saturates correctly through rcp.
__device__ __forceinline__ float tanh_fast(float t) {
    float e = __expf(2.0f * t);
    float r = __builtin_amdgcn_rcpf(e + 1.0f);
    return __builtin_fmaf(-2.0f, r, 1.0f);
}

// ---- f32 -> bf16 conversion of x, Ww, Wu (float4 granularity) ----
__global__ __launch_bounds__(256) void convert_kernel(
    const float* __restrict__ x, const float* __restrict__ Ww,
    const float* __restrict__ Wu, ushort* __restrict__ xb,
    ushort* __restrict__ Wwb, ushort* __restrict__ Wub)
{
    int i = blockIdx.x * 256 + threadIdx.x;  // float4 index
    const float* src; ushort* dst; int off;
    if (i < 524288)      { src = x;  dst = xb;  off = i; }
    else if (i < 589824) { src = Ww; dst = Wwb; off = i - 524288; }
    else                 { src = Wu; dst = Wub; off = i - 589824; }
    float4 v = ((const float4*)src)[off];
    ushort4 o;
    o.x = f2bf(v.x); o.y = f2bf(v.y); o.z = f2bf(v.z); o.w = f2bf(v.w);
    ((ushort4*)dst)[off] = o;
}

// ---- C[m][n] = sum_k A[m][k]*W[n][k], bf16 MFMA 16x16x32 ----
// z=0: Ww -> wx (f32).  z=1: Wu -> uxb (bf16).
__global__ __launch_bounds__(256) void dual_gemm_mfma(
    const ushort* __restrict__ xb, const ushort* __restrict__ Wwb,
    const ushort* __restrict__ Wub, float* __restrict__ wx, ushort* __restrict__ uxb)
{
    const ushort* B = blockIdx.z ? Wub : Wwb;
    const int m0 = blockIdx.x * 128;
    const int n0 = blockIdx.y * 64;

    __shared__ __align__(16) ushort As[128 * 64];  // [m][k] 16KB
    __shared__ __align__(16) ushort Bs[64 * 64];   // [n][k]  8KB

    const int tid  = threadIdx.x;
    const int wv   = tid >> 6;
    const int lane = tid & 63;
    const int wm   = (wv >> 1) * 64;
    const int wn   = (wv & 1) * 32;
    const int lr   = lane & 15;
    const int lg   = lane >> 4;

    f32x4 acc[4][2] = {};

    for (int k0 = 0; k0 < D_DIM; k0 += 64) {
        #pragma unroll
        for (int i = 0; i < 4; ++i) {
            int c = i * 256 + tid;
            const ushort* src = xb + (size_t)(m0 + (c >> 3)) * D_DIM + k0 + (c & 7) * 8;
            ushort* dst = As + (i * 256 + wv * 64) * 8;
            __builtin_amdgcn_global_load_lds(
                (const __attribute__((address_space(1))) void*)src,
                (__attribute__((address_space(3))) void*)dst, 16, 0, 0);
        }
        #pragma unroll
        for (int i = 0; i < 2; ++i) {
            int c = i * 256 + tid;
            const ushort* src = B + (size_t)(n0 + (c >> 3)) * D_DIM + k0 + (c & 7) * 8;
            ushort* dst = Bs + (i * 256 + wv * 64) * 8;
            __builtin_amdgcn_global_load_lds(
                (const __attribute__((address_space(1))) void*)src,
                (__attribute__((address_space(3))) void*)dst, 16, 0, 0);
        }
        __syncthreads();

        #pragma unroll
        for (int kk = 0; kk < 2; ++kk) {
            bf16x8 a[4], b[2];
            #pragma unroll
            for (int mi = 0; mi < 4; ++mi)
                a[mi] = *(const bf16x8*)&As[(wm + mi * 16 + lr) * 64 + kk * 32 + lg * 8];
            #pragma unroll
            for (int ni = 0; ni < 2; ++ni)
                b[ni] = *(const bf16x8*)&Bs[(wn + ni * 16 + lr) * 64 + kk * 32 + lg * 8];
            #pragma unroll
            for (int mi = 0; mi < 4; ++mi)
                #pragma unroll
                for (int ni = 0; ni < 2; ++ni)
                    acc[mi][ni] = __builtin_amdgcn_mfma_f32_16x16x32_bf16(
                        a[mi], b[ni], acc[mi][ni], 0, 0, 0);
        }
        __syncthreads();
    }

    // D layout: col = lane&15, row = (lane>>4)*4 + r
    if (blockIdx.z == 0) {
        #pragma unroll
        for (int mi = 0; mi < 4; ++mi)
            #pragma unroll
            for (int ni = 0; ni < 2; ++ni)
                #pragma unroll
                for (int r = 0; r < 4; ++r)
                    wx[(size_t)(m0 + wm + mi * 16 + lg * 4 + r) * H_DIM + n0 + wn + ni * 16 + lr] =
                        acc[mi][ni][r];
    } else {
        #pragma unroll
        for (int mi = 0; mi < 4; ++mi)
            #pragma unroll
            for (int ni = 0; ni < 2; ++ni)
                #pragma unroll
                for (int r = 0; r < 4; ++r)
                    uxb[(size_t)(m0 + wm + mi * 16 + lg * 4 + r) * H_DIM + n0 + wn + ni * 16 + lr] =
                        f2bf(acc[mi][ni][r]);
    }
}

// ---- fused scores/softmax/gather: LB l's per block, one wave per l ----
// ux rows staged once in LDS (bf16); tiny register state -> no spills.
__global__ __launch_bounds__(256, 4) void attn_kernel(
    const float* __restrict__ x, const float* __restrict__ wx,
    const ushort* __restrict__ uxb, const float* __restrict__ Wv,
    float* __restrict__ g)
{
    // XCD swizzle: grid=1024 (%8==0) -> 128 consecutive blocks per XCD
    const int bid  = (blockIdx.x & 7) * 128 + (blockIdx.x >> 3);
    const int l0   = bid * LB;
    const int tid  = threadIdx.x;
    const int wave = tid >> 6;
    const int lane = tid & 63;
    const int l    = l0 + wave;

    __shared__ __align__(16) ushort uxs[NROWS * H_DIM];  // 36 KB
    __shared__ float sc_lds[LB][32];
    __shared__ float at_lds[LB][32];

    // stage NROWS ux rows (bf16): wave `wave` loads row it*4+wave each iter.
    // OOB rows clamp the source (content unused; selected to 0 in compute).
    #pragma unroll
    for (int it = 0; it < NROWS / LB; ++it) {
        const int row = it * LB + wave;
        int n = l0 - P_PAD + row;
        n = min(max(n, 0), L_SEQ - 1);
        const ushort* src = uxb + (size_t)n * H_DIM + lane * 8;
        ushort* dst = uxs + (it * 256 + wave * 64) * 8;   // wave-uniform base
        __builtin_amdgcn_global_load_lds(
            (const __attribute__((address_space(1))) void*)src,
            (__attribute__((address_space(3))) void*)dst, 16, 0, 0);
    }

    // wx[l] and Wv slices held in registers (8 floats each per lane)
    float wxr[8], wvr[8];
    {
        float4 a0 = *(const float4*)&wx[(size_t)l * H_DIM + lane * 8];
        float4 a1 = *(const float4*)&wx[(size_t)l * H_DIM + lane * 8 + 4];
        float4 v0 = *(const float4*)&Wv[lane * 8];
        float4 v1 = *(const float4*)&Wv[lane * 8 + 4];
        wxr[0]=a0.x; wxr[1]=a0.y; wxr[2]=a0.z; wxr[3]=a0.w;
        wxr[4]=a1.x; wxr[5]=a1.y; wxr[6]=a1.z; wxr[7]=a1.w;
        wvr[0]=v0.x; wvr[1]=v0.y; wvr[2]=v0.z; wvr[3]=v0.w;
        wvr[4]=v1.x; wvr[5]=v1.y; wvr[6]=v1.z; wvr[7]=v1.w;
    }
    __syncthreads();

    // ---- phase 1: 32 window scores, 4 concurrent accumulators ----
    #pragma unroll
    for (int wg = 0; wg < 8; ++wg) {
        float acc[4] = {0.f, 0.f, 0.f, 0.f};
        #pragma unroll
        for (int wi = 0; wi < 4; ++wi) {
            const int w = wg * 4 + wi;
            const int j = (w < P_PAD) ? (w - P_PAD) : (w - P_PAD + 1);
            const int n = l + j;
            const bool valid = ((unsigned)n < (unsigned)L_SEQ);
            const int row = wave + P_PAD + j;        // always in [0, NROWS)
            u16x8 uv = *(const u16x8*)&uxs[row * H_DIM + lane * 8];
            #pragma unroll
            for (int e = 0; e < 8; ++e) {
                float uf = valid ? __uint_as_float((unsigned)uv[e] << 16) : 0.0f;
                acc[wi] = __builtin_fmaf(wvr[e], tanh_fast(wxr[e] + uf), acc[wi]);
            }
        }
        #pragma unroll
        for (int wi = 0; wi < 4; ++wi) {
            float v = acc[wi];
            #pragma unroll
            for (int off = 32; off; off >>= 1) v += __shfl_xor(v, off);
            if (lane == wg * 4 + wi) sc_lds[wave][wg * 4 + wi] = v;
        }
    }
    __syncthreads();

    // ---- phase 2: softmax over the 32 windows ----
    if (tid < LB * 32) {
        const int ll = tid >> 5, w = tid & 31;
        float sc = sc_lds[ll][w];
        float m = sc;
        #pragma unroll
        for (int off = 16; off; off >>= 1) m = fmaxf(m, __shfl_xor(m, off, 32));
        float e = __expf(sc - m);
        float sum = e;
        #pragma unroll
        for (int off = 16; off; off >>= 1) sum += __shfl_xor(sum, off, 32);
        at_lds[ll][w] = e * __builtin_amdgcn_rcpf(sum);
    }
    __syncthreads();

    // ---- phase 3: g[l][d] = sum_w attn*x[l+j][d]; share 36 x-rows ----
    const int d = tid * 2;
    float2 acc[LB];
    #pragma unroll
    for (int li = 0; li < LB; ++li) acc[li] = make_float2(0.f, 0.f);

    #pragma unroll
    for (int t = 0; t < NROWS; ++t) {
        const int n = l0 - P_PAD + t;
        if (n >= 0 && n < L_SEQ) {
            float2 xv = *(const float2*)&x[(size_t)n * D_DIM + d];
            #pragma unroll
            for (int li = 0; li < LB; ++li) {
                const int j = t - P_PAD - li;        // compile-time per (t,li)
                if (j >= -P_PAD && j <= P_PAD && j != 0) {
                    const int w = (j < 0) ? j + P_PAD : j + P_PAD - 1;
                    float a = at_lds[li][w];
                    acc[li].x = __builtin_fmaf(a, xv.x, acc[li].x);
                    acc[li].y = __builtin_fmaf(a, xv.y, acc[li].y);
                }
            }
        }
    }
    #pragma unroll
    for (int li = 0; li < LB; ++li)
        *(float2*)&g[(size_t)(l0 + li) * D_DIM + d] = acc[li];
}

extern "C" void kernel_launch(void* const* d_in, const int* in_sizes, int n_in,
                              void* d_out, int out_size, void* d_ws, size_t ws_size,
                              hipStream_t stream) {
    const float* x  = (const float*)d_in[0];
    const float* Ww = (const float*)d_in[1];
    const float* Wu = (const float*)d_in[2];
    const float* Wv = (const float*)d_in[3];
    float* g = (float*)d_out;

    float*  wx  = (float*)d_ws;                          // 8 MB f32 [L][H]
    ushort* uxb = (ushort*)(wx + (size_t)L_SEQ * H_DIM); // 4 MB bf16 [L][H]
    ushort* xb  = uxb + (size_t)L_SEQ * H_DIM;           // 4 MB
    ushort* Wwb = xb + (size_t)L_SEQ * D_DIM;            // 0.5 MB
    ushort* Wub = Wwb + (size_t)H_DIM * D_DIM;           // 0.5 MB

    convert_kernel<<<dim3(2560), 256, 0, stream>>>(x, Ww, Wu, xb, Wwb, Wub);
    dual_gemm_mfma<<<dim3(L_SEQ / 128, H_DIM / 64, 2), 256, 0, stream>>>(xb, Wwb, Wub, wx, uxb);
    attn_kernel<<<dim3(L_SEQ / LB), 256, 0, stream>>>(x, wx, uxb, Wv, g);
}

// Round 4
// 55.661 us; speedup vs baseline: 2.4022x; 1.1316x over previous
//
#include <hip/hip_runtime.h>

#define L_SEQ 4096
#define D_DIM 512
#define H_DIM 512
#define P_PAD 16
#define LB 4   // l-rows per attn block

typedef __bf16 bf16x8 __attribute__((ext_vector_type(8)));
typedef float  f32x4  __attribute__((ext_vector_type(4)));

__device__ __forceinline__ ushort f2bf(float f) {
    unsigned u = __float_as_uint(f);
    return (ushort)((u + 0x7FFFu + ((u >> 16) & 1u)) >> 16);   // RNE
}

// ---- f32 -> bf16 conversion of x, Ww, Wu (float4 granularity) ----
__global__ __launch_bounds__(256) void convert_kernel(
    const float* __restrict__ x, const float* __restrict__ Ww,
    const float* __restrict__ Wu, ushort* __restrict__ xb,
    ushort* __restrict__ Wwb, ushort* __restrict__ Wub)
{
    int i = blockIdx.x * 256 + threadIdx.x;  // float4 index
    const float* src; ushort* dst; int off;
    if (i < 524288)      { src = x;  dst = xb;  off = i; }
    else if (i < 589824) { src = Ww; dst = Wwb; off = i - 524288; }
    else                 { src = Wu; dst = Wub; off = i - 589824; }
    float4 v = ((const float4*)src)[off];
    ushort4 o;
    o.x = f2bf(v.x); o.y = f2bf(v.y); o.z = f2bf(v.z); o.w = f2bf(v.w);
    ((ushort4*)dst)[off] = o;
}

// ---- C[m][n] = sum_k A[m][k]*W[n][k], bf16 MFMA 16x16x32, f32 out ----
// z=0: Ww -> wx.  z=1: Wu -> ux.  Tile 128x64, BK=64, 4 waves 2x2.
__global__ __launch_bounds__(256, 4) void dual_gemm_mfma(
    const ushort* __restrict__ xb, const ushort* __restrict__ Wwb,
    const ushort* __restrict__ Wub, float* __restrict__ wx, float* __restrict__ ux)
{
    const ushort* B = blockIdx.z ? Wub : Wwb;
    float*       out = blockIdx.z ? ux : wx;
    const int m0 = blockIdx.x * 128;
    const int n0 = blockIdx.y * 64;

    __shared__ __align__(16) ushort As[128 * 64];  // 16KB
    __shared__ __align__(16) ushort Bs[64 * 64];   //  8KB

    const int tid  = threadIdx.x;
    const int wv   = tid >> 6;
    const int lane = tid & 63;
    const int wm   = (wv >> 1) * 64;
    const int wn   = (wv & 1) * 32;
    const int lr   = lane & 15;
    const int lg   = lane >> 4;

    f32x4 acc[4][2] = {};

    for (int k0 = 0; k0 < D_DIM; k0 += 64) {
        #pragma unroll
        for (int i = 0; i < 4; ++i) {
            int c = i * 256 + tid;
            const ushort* src = xb + (size_t)(m0 + (c >> 3)) * D_DIM + k0 + (c & 7) * 8;
            ushort* dst = As + (i * 256 + wv * 64) * 8;
            __builtin_amdgcn_global_load_lds(
                (const __attribute__((address_space(1))) void*)src,
                (__attribute__((address_space(3))) void*)dst, 16, 0, 0);
        }
        #pragma unroll
        for (int i = 0; i < 2; ++i) {
            int c = i * 256 + tid;
            const ushort* src = B + (size_t)(n0 + (c >> 3)) * D_DIM + k0 + (c & 7) * 8;
            ushort* dst = Bs + (i * 256 + wv * 64) * 8;
            __builtin_amdgcn_global_load_lds(
                (const __attribute__((address_space(1))) void*)src,
                (__attribute__((address_space(3))) void*)dst, 16, 0, 0);
        }
        __syncthreads();

        #pragma unroll
        for (int kk = 0; kk < 2; ++kk) {
            bf16x8 a[4], b[2];
            #pragma unroll
            for (int mi = 0; mi < 4; ++mi)
                a[mi] = *(const bf16x8*)&As[(wm + mi * 16 + lr) * 64 + kk * 32 + lg * 8];
            #pragma unroll
            for (int ni = 0; ni < 2; ++ni)
                b[ni] = *(const bf16x8*)&Bs[(wn + ni * 16 + lr) * 64 + kk * 32 + lg * 8];
            #pragma unroll
            for (int mi = 0; mi < 4; ++mi)
                #pragma unroll
                for (int ni = 0; ni < 2; ++ni)
                    acc[mi][ni] = __builtin_amdgcn_mfma_f32_16x16x32_bf16(
                        a[mi], b[ni], acc[mi][ni], 0, 0, 0);
        }
        __syncthreads();
    }

    // D layout: col = lane&15, row = (lane>>4)*4 + r
    #pragma unroll
    for (int mi = 0; mi < 4; ++mi)
        #pragma unroll
        for (int ni = 0; ni < 2; ++ni)
            #pragma unroll
            for (int r = 0; r < 4; ++r)
                out[(size_t)(m0 + wm + mi * 16 + lg * 4 + r) * H_DIM + n0 + wn + ni * 16 + lr] =
                    acc[mi][ni][r];
}

// ---- fused scores/softmax/gather; no LDS staging (ux is L2-resident) ----
// score(l,w) = const + sum_h (-2 wv[h]) * rcp(exp(2(wx+ux)) + 1); const drops
// in softmax. OOB windows fixed up once per wave (score with ux = 0).
__global__ __launch_bounds__(256, 6) void attn_kernel(
    const float* __restrict__ x, const float* __restrict__ wx,
    const float* __restrict__ ux, const float* __restrict__ Wv,
    float* __restrict__ g)
{
    // XCD swizzle: grid=1024 -> 128 consecutive blocks per XCD
    const int bid  = (blockIdx.x & 7) * 128 + (blockIdx.x >> 3);
    const int l0   = bid * LB;
    const int tid  = threadIdx.x;
    const int wave = tid >> 6;
    const int lane = tid & 63;
    const int l    = l0 + wave;

    __shared__ float sc_lds[LB][32];
    __shared__ float at_lds[LB][32];

    // wx[l]*2 and Wv*(-2) h-slices in registers (8 elems per lane)
    float wx2[8], wv2[8];
    {
        const f32x4* wxp = (const f32x4*)&wx[(size_t)l * H_DIM + lane * 8];
        const f32x4* wvp = (const f32x4*)&Wv[lane * 8];
        f32x4 a0 = wxp[0], a1 = wxp[1], v0 = wvp[0], v1 = wvp[1];
        #pragma unroll
        for (int e = 0; e < 4; ++e) {
            wx2[e]     = 2.0f * a0[e];
            wx2[e + 4] = 2.0f * a1[e];
            wv2[e]     = -2.0f * v0[e];
            wv2[e + 4] = -2.0f * v1[e];
        }
    }

    // ---- phase 1: 32 window scores, groups of 4 windows ----
    float sc = 0.0f;
    #pragma unroll
    for (int wg = 0; wg < 8; ++wg) {
        f32x4 u[8];
        #pragma unroll
        for (int wi = 0; wi < 4; ++wi) {
            const int w = wg * 4 + wi;
            const int j = (w < P_PAD) ? (w - P_PAD) : (w - P_PAD + 1);
            int n = l + j;
            n = min(max(n, 0), L_SEQ - 1);          // clamp; OOB fixed later
            const f32x4* p = (const f32x4*)(ux + (size_t)n * H_DIM + lane * 8);
            u[2 * wi]     = p[0];
            u[2 * wi + 1] = p[1];
        }
        float acc[4];
        #pragma unroll
        for (int wi = 0; wi < 4; ++wi) {
            float a = 0.0f;
            #pragma unroll
            for (int e = 0; e < 8; ++e) {
                float ue = u[2 * wi + (e >> 2)][e & 3];
                float r = __builtin_amdgcn_rcpf(
                    __expf(__builtin_fmaf(ue, 2.0f, wx2[e])) + 1.0f);
                a = __builtin_fmaf(wv2[e], r, a);
            }
            acc[wi] = a;
        }
        #pragma unroll
        for (int wi = 0; wi < 4; ++wi) {
            float v = acc[wi];
            #pragma unroll
            for (int off = 32; off; off >>= 1) v += __shfl_xor(v, off);
            sc = (lane == wg * 4 + wi) ? v : sc;
        }
    }

    // ---- OOB fix-up (only waves near sequence edges) ----
    if (l < P_PAD || l >= L_SEQ - P_PAD) {
        float a = 0.0f;
        #pragma unroll
        for (int e = 0; e < 8; ++e) {
            float r = __builtin_amdgcn_rcpf(__expf(wx2[e]) + 1.0f);
            a = __builtin_fmaf(wv2[e], r, a);
        }
        #pragma unroll
        for (int off = 32; off; off >>= 1) a += __shfl_xor(a, off);
        const int w = lane & 31;
        const int j = (w < P_PAD) ? (w - P_PAD) : (w - P_PAD + 1);
        const int n = l + j;
        if (n < 0 || n >= L_SEQ) sc = a;
    }
    if (lane < 32) sc_lds[wave][lane] = sc;
    __syncthreads();

    // ---- phase 2: softmax over the 32 windows ----
    if (tid < LB * 32) {
        const int ll = tid >> 5, w = tid & 31;
        float s0 = sc_lds[ll][w];
        float m = s0;
        #pragma unroll
        for (int off = 16; off; off >>= 1) m = fmaxf(m, __shfl_xor(m, off, 32));
        float e = __expf(s0 - m);
        float sum = e;
        #pragma unroll
        for (int off = 16; off; off >>= 1) sum += __shfl_xor(sum, off, 32);
        at_lds[ll][w] = e * __builtin_amdgcn_rcpf(sum);
    }
    __syncthreads();

    // ---- phase 3: g[l][d] = sum_w attn*x[l+j][d]; share 36 x-rows ----
    const int d = tid * 2;
    float2 acc[LB];
    #pragma unroll
    for (int li = 0; li < LB; ++li) acc[li] = make_float2(0.f, 0.f);

    #pragma unroll
    for (int t = 0; t < LB + 2 * P_PAD; ++t) {
        const int n = l0 - P_PAD + t;
        if (n >= 0 && n < L_SEQ) {
            float2 xv = *(const float2*)&x[(size_t)n * D_DIM + d];
            #pragma unroll
            for (int li = 0; li < LB; ++li) {
                const int j = t - P_PAD - li;        // compile-time per (t,li)
                if (j >= -P_PAD && j <= P_PAD && j != 0) {
                    const int w = (j < 0) ? j + P_PAD : j + P_PAD - 1;
                    float a = at_lds[li][w];
                    acc[li].x = __builtin_fmaf(a, xv.x, acc[li].x);
                    acc[li].y = __builtin_fmaf(a, xv.y, acc[li].y);
                }
            }
        }
    }
    #pragma unroll
    for (int li = 0; li < LB; ++li)
        *(float2*)&g[(size_t)(l0 + li) * D_DIM + d] = acc[li];
}

extern "C" void kernel_launch(void* const* d_in, const int* in_sizes, int n_in,
                              void* d_out, int out_size, void* d_ws, size_t ws_size,
                              hipStream_t stream) {
    const float* x  = (const float*)d_in[0];
    const float* Ww = (const float*)d_in[1];
    const float* Wu = (const float*)d_in[2];
    const float* Wv = (const float*)d_in[3];
    float* g = (float*)d_out;

    float*  wx  = (float*)d_ws;                          // 8 MB f32 [L][H]
    float*  ux  = wx + (size_t)L_SEQ * H_DIM;            // 8 MB f32 [L][H]
    ushort* xb  = (ushort*)(ux + (size_t)L_SEQ * H_DIM); // 4 MB
    ushort* Wwb = xb + (size_t)L_SEQ * D_DIM;            // 0.5 MB
    ushort* Wub = Wwb + (size_t)H_DIM * D_DIM;           // 0.5 MB

    convert_kernel<<<dim3(2560), 256, 0, stream>>>(x, Ww, Wu, xb, Wwb, Wub);
    dual_gemm_mfma<<<dim3(L_SEQ / 128, H_DIM / 64, 2), 256, 0, stream>>>(xb, Wwb, Wub, wx, ux);
    attn_kernel<<<dim3(L_SEQ / LB), 256, 0, stream>>>(x, wx, ux, Wv, g);
}

// Round 5
// 51.973 us; speedup vs baseline: 2.5727x; 1.0710x over previous
//
#include <hip/hip_runtime.h>

#define L_SEQ 4096
#define D_DIM 512
#define H_DIM 512
#define P_PAD 16
#define LB 4
#define LOG2E2 2.885390081777927f   // 2*log2(e)

typedef __bf16 bf16x8 __attribute__((ext_vector_type(8)));
typedef float  f32x4  __attribute__((ext_vector_type(4)));

#if __has_builtin(__builtin_amdgcn_exp2f)
#define EXP2F(x) __builtin_amdgcn_exp2f(x)
#else
#define EXP2F(x) __expf((x) * 0.6931471805599453f)
#endif

__device__ __forceinline__ ushort f2bf(float f) {
    unsigned u = __float_as_uint(f);
    return (ushort)((u + 0x7FFFu + ((u >> 16) & 1u)) >> 16);   // RNE
}

// ---- f32 -> bf16 conversion of x, Ww, Wu (float4 granularity) ----
__global__ __launch_bounds__(256) void convert_kernel(
    const float* __restrict__ x, const float* __restrict__ Ww,
    const float* __restrict__ Wu, ushort* __restrict__ xb,
    ushort* __restrict__ Wwb, ushort* __restrict__ Wub)
{
    int i = blockIdx.x * 256 + threadIdx.x;  // float4 index
    const float* src; ushort* dst; int off;
    if (i < 524288)      { src = x;  dst = xb;  off = i; }
    else if (i < 589824) { src = Ww; dst = Wwb; off = i - 524288; }
    else                 { src = Wu; dst = Wub; off = i - 589824; }
    float4 v = ((const float4*)src)[off];
    ushort4 o;
    o.x = f2bf(v.x); o.y = f2bf(v.y); o.z = f2bf(v.z); o.w = f2bf(v.w);
    ((ushort4*)dst)[off] = o;
}

// ---- C[m][n] = sum_k A[m][k]*W[n][k], bf16 MFMA, 2-phase dbuf + XOR swizzle ----
// z=0: Ww -> wx.  z=1: Wu -> ux.  Tile 128x64, BK=64, 4 waves 2x2.
__global__ __launch_bounds__(256, 2) void dual_gemm_mfma(
    const ushort* __restrict__ xb, const ushort* __restrict__ Wwb,
    const ushort* __restrict__ Wub, float* __restrict__ wx, float* __restrict__ ux)
{
    const ushort* Bm = blockIdx.z ? Wub : Wwb;
    float*       out = blockIdx.z ? ux : wx;
    const int m0 = blockIdx.x * 128;
    const int n0 = blockIdx.y * 64;

    __shared__ __align__(16) ushort As[2][128 * 64];  // 2 x 16KB
    __shared__ __align__(16) ushort Bs[2][64 * 64];   // 2 x  8KB

    const int tid  = threadIdx.x;
    const int wv   = tid >> 6;
    const int lane = tid & 63;
    const int wm   = (wv >> 1) * 64;
    const int wn   = (wv & 1) * 32;
    const int lr   = lane & 15;
    const int lg   = lane >> 4;
    const int rx   = lr & 7;   // read-side swizzle key (row&7 == lr&7 here)

    f32x4 acc[4][2] = {};

    // Stage with inverse-swizzled GLOBAL source + linear LDS dest (m201 pattern):
    // LDS chunk slot q of row r holds global chunk q ^ (r&7).
    auto stage = [&](int t, int buf) {
        const int k0 = t * 64;
        #pragma unroll
        for (int i = 0; i < 4; ++i) {
            int c = i * 256 + tid;
            int row = c >> 3, q = c & 7;
            const ushort* src = xb + (size_t)(m0 + row) * D_DIM + k0 + ((q ^ (row & 7)) * 8);
            ushort* dst = &As[buf][(i * 256 + wv * 64) * 8];
            __builtin_amdgcn_global_load_lds(
                (const __attribute__((address_space(1))) void*)src,
                (__attribute__((address_space(3))) void*)dst, 16, 0, 0);
        }
        #pragma unroll
        for (int i = 0; i < 2; ++i) {
            int c = i * 256 + tid;
            int row = c >> 3, q = c & 7;
            const ushort* src = Bm + (size_t)(n0 + row) * D_DIM + k0 + ((q ^ (row & 7)) * 8);
            ushort* dst = &Bs[buf][(i * 256 + wv * 64) * 8];
            __builtin_amdgcn_global_load_lds(
                (const __attribute__((address_space(1))) void*)src,
                (__attribute__((address_space(3))) void*)dst, 16, 0, 0);
        }
    };

    auto compute = [&](int buf) {
        #pragma unroll
        for (int kk = 0; kk < 2; ++kk) {
            bf16x8 a[4], b[2];
            #pragma unroll
            for (int mi = 0; mi < 4; ++mi)
                a[mi] = *(const bf16x8*)&As[buf][(wm + mi * 16 + lr) * 64 +
                                                 (((kk * 4 + lg) ^ rx) * 8)];
            #pragma unroll
            for (int ni = 0; ni < 2; ++ni)
                b[ni] = *(const bf16x8*)&Bs[buf][(wn + ni * 16 + lr) * 64 +
                                                 (((kk * 4 + lg) ^ rx) * 8)];
            #pragma unroll
            for (int mi = 0; mi < 4; ++mi)
                #pragma unroll
                for (int ni = 0; ni < 2; ++ni)
                    acc[mi][ni] = __builtin_amdgcn_mfma_f32_16x16x32_bf16(
                        a[mi], b[ni], acc[mi][ni], 0, 0, 0);
        }
    };

    stage(0, 0);
    __syncthreads();
    #pragma unroll
    for (int t = 0; t < 7; ++t) {
        stage(t + 1, (t + 1) & 1);   // issue next-tile loads (in flight over MFMA)
        compute(t & 1);
        __syncthreads();             // drains stage(t+1) + read-done for overwrite
    }
    compute(1);

    // D layout: col = lane&15, row = (lane>>4)*4 + r
    #pragma unroll
    for (int mi = 0; mi < 4; ++mi)
        #pragma unroll
        for (int ni = 0; ni < 2; ++ni)
            #pragma unroll
            for (int r = 0; r < 4; ++r)
                out[(size_t)(m0 + wm + mi * 16 + lg * 4 + r) * H_DIM + n0 + wn + ni * 16 + lr] =
                    acc[mi][ni][r];
}

// ---- fused scores/softmax/gather; register-pipelined ux loads ----
__global__ __launch_bounds__(256, 4) void attn_kernel(
    const float* __restrict__ x, const float* __restrict__ wx,
    const float* __restrict__ ux, const float* __restrict__ Wv,
    float* __restrict__ g)
{
    // XCD swizzle: grid=1024 -> 128 consecutive blocks per XCD
    const int bid  = (blockIdx.x & 7) * 128 + (blockIdx.x >> 3);
    const int l0   = bid * LB;
    const int tid  = threadIdx.x;
    const int wave = tid >> 6;
    const int lane = tid & 63;
    const int l    = l0 + wave;

    __shared__ float sc_lds[LB][32];
    __shared__ float at_lds[LB][32];

    // wxs = (2 log2e) * wx[l], wvn = -2 * Wv; score' = sum wvn * rcp(exp2(...)+1)
    float wxs[8], wvn[8];
    {
        const f32x4* wxp = (const f32x4*)&wx[(size_t)l * H_DIM + lane * 8];
        const f32x4* wvp = (const f32x4*)&Wv[lane * 8];
        f32x4 a0 = wxp[0], a1 = wxp[1], v0 = wvp[0], v1 = wvp[1];
        #pragma unroll
        for (int e = 0; e < 4; ++e) {
            wxs[e]     = LOG2E2 * a0[e];
            wxs[e + 4] = LOG2E2 * a1[e];
            wvn[e]     = -2.0f * v0[e];
            wvn[e + 4] = -2.0f * v1[e];
        }
    }

    // ---- phase 1: 32 window scores; 2-deep register pipeline over groups of 4 ----
    f32x4 u[2][4][2];
    auto load_grp = [&](int wg, int buf) {
        #pragma unroll
        for (int wi = 0; wi < 4; ++wi) {
            const int w = wg * 4 + wi;
            const int j = (w < P_PAD) ? (w - P_PAD) : (w - P_PAD + 1);
            int n = l + j;
            n = min(max(n, 0), L_SEQ - 1);          // clamp; OOB fixed later
            const f32x4* p = (const f32x4*)(ux + (size_t)n * H_DIM + lane * 8);
            u[buf][wi][0] = p[0];
            u[buf][wi][1] = p[1];
        }
    };

    float sc = 0.0f;
    load_grp(0, 0);
    #pragma unroll
    for (int wg = 0; wg < 8; ++wg) {
        if (wg < 7) load_grp(wg + 1, (wg + 1) & 1);
        const int buf = wg & 1;
        float a4[4];
        #pragma unroll
        for (int wi = 0; wi < 4; ++wi) {
            float a = 0.0f;
            #pragma unroll
            for (int e = 0; e < 8; ++e) {
                float ue = u[buf][wi][e >> 2][e & 3];
                float p  = EXP2F(__builtin_fmaf(ue, LOG2E2, wxs[e]));
                a = __builtin_fmaf(wvn[e], __builtin_amdgcn_rcpf(p + 1.0f), a);
            }
            a4[wi] = a;
        }
        #pragma unroll
        for (int wi = 0; wi < 4; ++wi) {
            float v = a4[wi];
            #pragma unroll
            for (int off = 32; off; off >>= 1) v += __shfl_xor(v, off);
            sc = (lane == wg * 4 + wi) ? v : sc;
        }
    }

    // ---- OOB fix-up (waves near sequence edges): score with ux = 0 ----
    if (l < P_PAD || l >= L_SEQ - P_PAD) {
        float a = 0.0f;
        #pragma unroll
        for (int e = 0; e < 8; ++e) {
            float p = EXP2F(wxs[e]);
            a = __builtin_fmaf(wvn[e], __builtin_amdgcn_rcpf(p + 1.0f), a);
        }
        #pragma unroll
        for (int off = 32; off; off >>= 1) a += __shfl_xor(a, off);
        const int w = lane & 31;
        const int j = (w < P_PAD) ? (w - P_PAD) : (w - P_PAD + 1);
        const int n = l + j;
        if (n < 0 || n >= L_SEQ) sc = a;
    }
    if (lane < 32) sc_lds[wave][lane] = sc;
    __syncthreads();

    // ---- phase 2: softmax over the 32 windows ----
    if (tid < LB * 32) {
        const int ll = tid >> 5, w = tid & 31;
        float s0 = sc_lds[ll][w];
        float m = s0;
        #pragma unroll
        for (int off = 16; off; off >>= 1) m = fmaxf(m, __shfl_xor(m, off, 32));
        float e = __expf(s0 - m);
        float sum = e;
        #pragma unroll
        for (int off = 16; off; off >>= 1) sum += __shfl_xor(sum, off, 32);
        at_lds[ll][w] = e * __builtin_amdgcn_rcpf(sum);
    }
    __syncthreads();

    // ---- phase 3: g[l][d] = sum_w attn*x[l+j][d]; share 36 x-rows ----
    const int d = tid * 2;
    float2 acc[LB];
    #pragma unroll
    for (int li = 0; li < LB; ++li) acc[li] = make_float2(0.f, 0.f);

    #pragma unroll
    for (int t = 0; t < LB + 2 * P_PAD; ++t) {
        const int n = l0 - P_PAD + t;
        if (n >= 0 && n < L_SEQ) {
            float2 xv = *(const float2*)&x[(size_t)n * D_DIM + d];
            #pragma unroll
            for (int li = 0; li < LB; ++li) {
                const int j = t - P_PAD - li;        // compile-time per (t,li)
                if (j >= -P_PAD && j <= P_PAD && j != 0) {
                    const int w = (j < 0) ? j + P_PAD : j + P_PAD - 1;
                    float a = at_lds[li][w];
                    acc[li].x = __builtin_fmaf(a, xv.x, acc[li].x);
                    acc[li].y = __builtin_fmaf(a, xv.y, acc[li].y);
                }
            }
        }
    }
    #pragma unroll
    for (int li = 0; li < LB; ++li)
        *(float2*)&g[(size_t)(l0 + li) * D_DIM + d] = acc[li];
}

extern "C" void kernel_launch(void* const* d_in, const int* in_sizes, int n_in,
                              void* d_out, int out_size, void* d_ws, size_t ws_size,
                              hipStream_t stream) {
    const float* x  = (const float*)d_in[0];
    const float* Ww = (const float*)d_in[1];
    const float* Wu = (const float*)d_in[2];
    const float* Wv = (const float*)d_in[3];
    float* g = (float*)d_out;

    float*  wx  = (float*)d_ws;                          // 8 MB f32 [L][H]
    float*  ux  = wx + (size_t)L_SEQ * H_DIM;            // 8 MB f32 [L][H]
    ushort* xb  = (ushort*)(ux + (size_t)L_SEQ * H_DIM); // 4 MB
    ushort* Wwb = xb + (size_t)L_SEQ * D_DIM;            // 0.5 MB
    ushort* Wub = Wwb + (size_t)H_DIM * D_DIM;           // 0.5 MB

    convert_kernel<<<dim3(2560), 256, 0, stream>>>(x, Ww, Wu, xb, Wwb, Wub);
    dual_gemm_mfma<<<dim3(L_SEQ / 128, H_DIM / 64, 2), 256, 0, stream>>>(xb, Wwb, Wub, wx, ux);
    attn_kernel<<<dim3(L_SEQ / LB), 256, 0, stream>>>(x, wx, ux, Wv, g);
}

// Round 6
// 47.873 us; speedup vs baseline: 2.7930x; 1.0856x over previous
//
#include <hip/hip_runtime.h>

#define L_SEQ 4096
#define D_DIM 512
#define H_DIM 512
#define P_PAD 16
#define LB 4
#define LOG2E2 2.885390081777927f   // 2*log2(e)
#define LOG2E  1.4426950408889634f

typedef __bf16 bf16x8 __attribute__((ext_vector_type(8)));
typedef float  f32x4  __attribute__((ext_vector_type(4)));

extern "C" __device__ float __ocml_native_exp2_f32(float);

__device__ __forceinline__ float exp2_fast(float x) {
#if __has_builtin(__builtin_amdgcn_exp2f)
    return __builtin_amdgcn_exp2f(x);
#else
    return __ocml_native_exp2_f32(x);   // single v_exp_f32
#endif
}

__device__ __forceinline__ ushort f2bf(float f) {
    unsigned u = __float_as_uint(f);
    return (ushort)((u + 0x7FFFu + ((u >> 16) & 1u)) >> 16);   // RNE
}

// ---- f32 -> bf16 conversion of x, Ww, Wu (float4 granularity) ----
__global__ __launch_bounds__(256) void convert_kernel(
    const float* __restrict__ x, const float* __restrict__ Ww,
    const float* __restrict__ Wu, ushort* __restrict__ xb,
    ushort* __restrict__ Wwb, ushort* __restrict__ Wub)
{
    int i = blockIdx.x * 256 + threadIdx.x;  // float4 index
    const float* src; ushort* dst; int off;
    if (i < 524288)      { src = x;  dst = xb;  off = i; }
    else if (i < 589824) { src = Ww; dst = Wwb; off = i - 524288; }
    else                 { src = Wu; dst = Wub; off = i - 589824; }
    float4 v = ((const float4*)src)[off];
    ushort4 o;
    o.x = f2bf(v.x); o.y = f2bf(v.y); o.z = f2bf(v.z); o.w = f2bf(v.w);
    ((ushort4*)dst)[off] = o;
}

// ---- E[m][n] = exp2(LOG2E2 * sum_k A[m][k]*W[n][k]) via bf16 MFMA ----
// z=0: Ww -> Ew.  z=1: Wu -> Eu.  Tile 128x64, BK=64, dbuf + XOR swizzle.
__global__ __launch_bounds__(256, 2) void dual_gemm_mfma(
    const ushort* __restrict__ xb, const ushort* __restrict__ Wwb,
    const ushort* __restrict__ Wub, float* __restrict__ Ew, float* __restrict__ Eu)
{
    const ushort* Bm = blockIdx.z ? Wub : Wwb;
    float*       out = blockIdx.z ? Eu : Ew;
    const int m0 = blockIdx.x * 128;
    const int n0 = blockIdx.y * 64;

    __shared__ __align__(16) ushort As[2][128 * 64];  // 2 x 16KB
    __shared__ __align__(16) ushort Bs[2][64 * 64];   // 2 x  8KB

    const int tid  = threadIdx.x;
    const int wv   = tid >> 6;
    const int lane = tid & 63;
    const int wm   = (wv >> 1) * 64;
    const int wn   = (wv & 1) * 32;
    const int lr   = lane & 15;
    const int lg   = lane >> 4;
    const int rx   = lr & 7;   // read-side swizzle key

    f32x4 acc[4][2] = {};

    // LDS stays linear; global source chunk q ^ (row&7) (involution, m201 pattern)
    auto stage = [&](int t, int buf) {
        const int k0 = t * 64;
        #pragma unroll
        for (int i = 0; i < 4; ++i) {
            int c = i * 256 + tid;
            int row = c >> 3, q = c & 7;
            const ushort* src = xb + (size_t)(m0 + row) * D_DIM + k0 + ((q ^ (row & 7)) * 8);
            ushort* dst = &As[buf][(i * 256 + wv * 64) * 8];
            __builtin_amdgcn_global_load_lds(
                (const __attribute__((address_space(1))) void*)src,
                (__attribute__((address_space(3))) void*)dst, 16, 0, 0);
        }
        #pragma unroll
        for (int i = 0; i < 2; ++i) {
            int c = i * 256 + tid;
            int row = c >> 3, q = c & 7;
            const ushort* src = Bm + (size_t)(n0 + row) * D_DIM + k0 + ((q ^ (row & 7)) * 8);
            ushort* dst = &Bs[buf][(i * 256 + wv * 64) * 8];
            __builtin_amdgcn_global_load_lds(
                (const __attribute__((address_space(1))) void*)src,
                (__attribute__((address_space(3))) void*)dst, 16, 0, 0);
        }
    };

    auto compute = [&](int buf) {
        #pragma unroll
        for (int kk = 0; kk < 2; ++kk) {
            bf16x8 a[4], b[2];
            #pragma unroll
            for (int mi = 0; mi < 4; ++mi)
                a[mi] = *(const bf16x8*)&As[buf][(wm + mi * 16 + lr) * 64 +
                                                 (((kk * 4 + lg) ^ rx) * 8)];
            #pragma unroll
            for (int ni = 0; ni < 2; ++ni)
                b[ni] = *(const bf16x8*)&Bs[buf][(wn + ni * 16 + lr) * 64 +
                                                 (((kk * 4 + lg) ^ rx) * 8)];
            #pragma unroll
            for (int mi = 0; mi < 4; ++mi)
                #pragma unroll
                for (int ni = 0; ni < 2; ++ni)
                    acc[mi][ni] = __builtin_amdgcn_mfma_f32_16x16x32_bf16(
                        a[mi], b[ni], acc[mi][ni], 0, 0, 0);
        }
    };

    stage(0, 0);
    __syncthreads();
    #pragma unroll
    for (int t = 0; t < 7; ++t) {
        stage(t + 1, (t + 1) & 1);
        compute(t & 1);
        __syncthreads();
    }
    compute(1);

    // D layout: col = lane&15, row = (lane>>4)*4 + r.  Write E = exp2(c*val).
    #pragma unroll
    for (int mi = 0; mi < 4; ++mi)
        #pragma unroll
        for (int ni = 0; ni < 2; ++ni)
            #pragma unroll
            for (int r = 0; r < 4; ++r)
                out[(size_t)(m0 + wm + mi * 16 + lg * 4 + r) * H_DIM + n0 + wn + ni * 16 + lr] =
                    exp2_fast(LOG2E2 * acc[mi][ni][r]);
}

// ---- phase 1: 32 window scores from Ew (regs) and Eu (L2 loads) ----
// score'(l,w) = sum_h wvn[h] * rcp(1 + Ew[l,h]*Eu[l+j,h]); softmax-equivalent.
template<bool EDGE>
__device__ __forceinline__ float score_phase(
    const float* __restrict__ Eu, int l, int lane,
    const float* ewr, const float* wvn)
{
    const float* base = Eu + (size_t)l * H_DIM + lane * 8;
    f32x4 u[2][4][2];
    auto load_grp = [&](int wg, int buf) {
        #pragma unroll
        for (int wi = 0; wi < 4; ++wi) {
            const int w = wg * 4 + wi;
            const int j = (w < P_PAD) ? (w - P_PAD) : (w - P_PAD + 1);
            const float* p;
            if (EDGE) {
                int n = l + j;
                n = min(max(n, 0), L_SEQ - 1);      // clamp; fixed up below
                p = Eu + (size_t)n * H_DIM + lane * 8;
            } else {
                p = base + j * H_DIM;               // compile-time offset
            }
            u[buf][wi][0] = ((const f32x4*)p)[0];
            u[buf][wi][1] = ((const f32x4*)p)[1];
        }
    };

    float sc = 0.0f;
    load_grp(0, 0);
    #pragma unroll
    for (int wg = 0; wg < 8; ++wg) {
        if (wg < 7) load_grp(wg + 1, (wg + 1) & 1);
        const int buf = wg & 1;
        float a4[4];
        #pragma unroll
        for (int wi = 0; wi < 4; ++wi) {
            float a = 0.0f;
            #pragma unroll
            for (int e = 0; e < 8; ++e) {
                float eu = u[buf][wi][e >> 2][e & 3];
                float q  = __builtin_fmaf(ewr[e], eu, 1.0f);
                a = __builtin_fmaf(wvn[e], __builtin_amdgcn_rcpf(q), a);
            }
            a4[wi] = a;
        }
        #pragma unroll
        for (int wi = 0; wi < 4; ++wi) {
            float v = a4[wi];
            #pragma unroll
            for (int off = 32; off; off >>= 1) v += __shfl_xor(v, off);
            sc = (lane == wg * 4 + wi) ? v : sc;
        }
    }

    if (EDGE) {   // OOB windows: score with ux = 0  ->  rcp(1 + Ew)
        float a = 0.0f;
        #pragma unroll
        for (int e = 0; e < 8; ++e)
            a = __builtin_fmaf(wvn[e], __builtin_amdgcn_rcpf(ewr[e] + 1.0f), a);
        #pragma unroll
        for (int off = 32; off; off >>= 1) a += __shfl_xor(a, off);
        const int w = lane & 31;
        const int j = (w < P_PAD) ? (w - P_PAD) : (w - P_PAD + 1);
        const int n = l + j;
        if (n < 0 || n >= L_SEQ) sc = a;
    }
    return sc;
}

__global__ __launch_bounds__(256, 4) void attn_kernel(
    const float* __restrict__ x, const float* __restrict__ Ew,
    const float* __restrict__ Eu, const float* __restrict__ Wv,
    float* __restrict__ g)
{
    // XCD swizzle: grid=1024 -> 128 consecutive blocks per XCD
    const int bid  = (blockIdx.x & 7) * 128 + (blockIdx.x >> 3);
    const int l0   = bid * LB;
    const int tid  = threadIdx.x;
    const int wave = tid >> 6;
    const int lane = tid & 63;
    const int l    = l0 + wave;

    __shared__ float sc_lds[LB][32];
    __shared__ float at_lds[LB][32];

    float ewr[8], wvn[8];
    {
        const f32x4* ewp = (const f32x4*)&Ew[(size_t)l * H_DIM + lane * 8];
        const f32x4* wvp = (const f32x4*)&Wv[lane * 8];
        f32x4 a0 = ewp[0], a1 = ewp[1], v0 = wvp[0], v1 = wvp[1];
        #pragma unroll
        for (int e = 0; e < 4; ++e) {
            ewr[e]     = a0[e];
            ewr[e + 4] = a1[e];
            wvn[e]     = -2.0f * v0[e];
            wvn[e + 4] = -2.0f * v1[e];
        }
    }

    float sc;
    if (l0 >= P_PAD && l0 + LB + P_PAD <= L_SEQ)
        sc = score_phase<false>(Eu, l, lane, ewr, wvn);
    else
        sc = score_phase<true>(Eu, l, lane, ewr, wvn);

    if (lane < 32) sc_lds[wave][lane] = sc;
    __syncthreads();

    // ---- phase 2: softmax over the 32 windows ----
    if (tid < LB * 32) {
        const int ll = tid >> 5, w = tid & 31;
        float s0 = sc_lds[ll][w];
        float m = s0;
        #pragma unroll
        for (int off = 16; off; off >>= 1) m = fmaxf(m, __shfl_xor(m, off, 32));
        float e = exp2_fast((s0 - m) * LOG2E);
        float sum = e;
        #pragma unroll
        for (int off = 16; off; off >>= 1) sum += __shfl_xor(sum, off, 32);
        at_lds[ll][w] = e * __builtin_amdgcn_rcpf(sum);
    }
    __syncthreads();

    // ---- phase 3: g[l][d] = sum_w attn*x[l+j][d]; share 36 x-rows ----
    const int d = tid * 2;
    float2 acc[LB];
    #pragma unroll
    for (int li = 0; li < LB; ++li) acc[li] = make_float2(0.f, 0.f);

    #pragma unroll
    for (int t = 0; t < LB + 2 * P_PAD; ++t) {
        const int n = l0 - P_PAD + t;
        if (n >= 0 && n < L_SEQ) {
            float2 xv = *(const float2*)&x[(size_t)n * D_DIM + d];
            #pragma unroll
            for (int li = 0; li < LB; ++li) {
                const int j = t - P_PAD - li;        // compile-time per (t,li)
                if (j >= -P_PAD && j <= P_PAD && j != 0) {
                    const int w = (j < 0) ? j + P_PAD : j + P_PAD - 1;
                    float a = at_lds[li][w];
                    acc[li].x = __builtin_fmaf(a, xv.x, acc[li].x);
                    acc[li].y = __builtin_fmaf(a, xv.y, acc[li].y);
                }
            }
        }
    }
    #pragma unroll
    for (int li = 0; li < LB; ++li)
        *(float2*)&g[(size_t)(l0 + li) * D_DIM + d] = acc[li];
}

extern "C" void kernel_launch(void* const* d_in, const int* in_sizes, int n_in,
                              void* d_out, int out_size, void* d_ws, size_t ws_size,
                              hipStream_t stream) {
    const float* x  = (const float*)d_in[0];
    const float* Ww = (const float*)d_in[1];
    const float* Wu = (const float*)d_in[2];
    const float* Wv = (const float*)d_in[3];
    float* g = (float*)d_out;

    float*  Ew  = (float*)d_ws;                          // 8 MB f32 [L][H]
    float*  Eu  = Ew + (size_t)L_SEQ * H_DIM;            // 8 MB f32 [L][H]
    ushort* xb  = (ushort*)(Eu + (size_t)L_SEQ * H_DIM); // 4 MB
    ushort* Wwb = xb + (size_t)L_SEQ * D_DIM;            // 0.5 MB
    ushort* Wub = Wwb + (size_t)H_DIM * D_DIM;           // 0.5 MB

    convert_kernel<<<dim3(2560), 256, 0, stream>>>(x, Ww, Wu, xb, Wwb, Wub);
    dual_gemm_mfma<<<dim3(L_SEQ / 128, H_DIM / 64, 2), 256, 0, stream>>>(xb, Wwb, Wub, Ew, Eu);
    attn_kernel<<<dim3(L_SEQ / LB), 256, 0, stream>>>(x, Ew, Eu, Wv, g);
}

// Round 7
// 45.793 us; speedup vs baseline: 2.9199x; 1.0454x over previous
//
#include <hip/hip_runtime.h>

#define L_SEQ 4096
#define D_DIM 512
#define H_DIM 512
#define P_PAD 16
#define LB 4
#define LOG2E2 2.885390081777927f   // 2*log2(e)
#define LOG2E  1.4426950408889634f

typedef __bf16 bf16x8 __attribute__((ext_vector_type(8)));
typedef float  f32x4  __attribute__((ext_vector_type(4)));

extern "C" __device__ float __ocml_native_exp2_f32(float);

__device__ __forceinline__ float exp2_fast(float x) {
#if __has_builtin(__builtin_amdgcn_exp2f)
    return __builtin_amdgcn_exp2f(x);
#else
    return __ocml_native_exp2_f32(x);   // single v_exp_f32
#endif
}

__device__ __forceinline__ ushort f2bf(float f) {
    unsigned u = __float_as_uint(f);
    return (ushort)((u + 0x7FFFu + ((u >> 16) & 1u)) >> 16);   // RNE
}

// ---- f32 -> bf16 conversion of x, Ww, Wu (float4 granularity) ----
__global__ __launch_bounds__(256) void convert_kernel(
    const float* __restrict__ x, const float* __restrict__ Ww,
    const float* __restrict__ Wu, ushort* __restrict__ xb,
    ushort* __restrict__ Wwb, ushort* __restrict__ Wub)
{
    int i = blockIdx.x * 256 + threadIdx.x;  // float4 index
    const float* src; ushort* dst; int off;
    if (i < 524288)      { src = x;  dst = xb;  off = i; }
    else if (i < 589824) { src = Ww; dst = Wwb; off = i - 524288; }
    else                 { src = Wu; dst = Wub; off = i - 589824; }
    float4 v = ((const float4*)src)[off];
    ushort4 o;
    o.x = f2bf(v.x); o.y = f2bf(v.y); o.z = f2bf(v.z); o.w = f2bf(v.w);
    ((ushort4*)dst)[off] = o;
}

// ---- E[m][n] = exp2(LOG2E2 * sum_k A[m][k]*W[n][k]) via bf16 MFMA ----
__global__ __launch_bounds__(256, 2) void dual_gemm_mfma(
    const ushort* __restrict__ xb, const ushort* __restrict__ Wwb,
    const ushort* __restrict__ Wub, float* __restrict__ Ew, float* __restrict__ Eu)
{
    const ushort* Bm = blockIdx.z ? Wub : Wwb;
    float*       out = blockIdx.z ? Eu : Ew;
    const int m0 = blockIdx.x * 128;
    const int n0 = blockIdx.y * 64;

    __shared__ __align__(16) ushort As[2][128 * 64];  // 2 x 16KB
    __shared__ __align__(16) ushort Bs[2][64 * 64];   // 2 x  8KB

    const int tid  = threadIdx.x;
    const int wv   = tid >> 6;
    const int lane = tid & 63;
    const int wm   = (wv >> 1) * 64;
    const int wn   = (wv & 1) * 32;
    const int lr   = lane & 15;
    const int lg   = lane >> 4;
    const int rx   = lr & 7;   // read-side swizzle key

    f32x4 acc[4][2] = {};

    auto stage = [&](int t, int buf) {
        const int k0 = t * 64;
        #pragma unroll
        for (int i = 0; i < 4; ++i) {
            int c = i * 256 + tid;
            int row = c >> 3, q = c & 7;
            const ushort* src = xb + (size_t)(m0 + row) * D_DIM + k0 + ((q ^ (row & 7)) * 8);
            ushort* dst = &As[buf][(i * 256 + wv * 64) * 8];
            __builtin_amdgcn_global_load_lds(
                (const __attribute__((address_space(1))) void*)src,
                (__attribute__((address_space(3))) void*)dst, 16, 0, 0);
        }
        #pragma unroll
        for (int i = 0; i < 2; ++i) {
            int c = i * 256 + tid;
            int row = c >> 3, q = c & 7;
            const ushort* src = Bm + (size_t)(n0 + row) * D_DIM + k0 + ((q ^ (row & 7)) * 8);
            ushort* dst = &Bs[buf][(i * 256 + wv * 64) * 8];
            __builtin_amdgcn_global_load_lds(
                (const __attribute__((address_space(1))) void*)src,
                (__attribute__((address_space(3))) void*)dst, 16, 0, 0);
        }
    };

    auto compute = [&](int buf) {
        #pragma unroll
        for (int kk = 0; kk < 2; ++kk) {
            bf16x8 a[4], b[2];
            #pragma unroll
            for (int mi = 0; mi < 4; ++mi)
                a[mi] = *(const bf16x8*)&As[buf][(wm + mi * 16 + lr) * 64 +
                                                 (((kk * 4 + lg) ^ rx) * 8)];
            #pragma unroll
            for (int ni = 0; ni < 2; ++ni)
                b[ni] = *(const bf16x8*)&Bs[buf][(wn + ni * 16 + lr) * 64 +
                                                 (((kk * 4 + lg) ^ rx) * 8)];
            #pragma unroll
            for (int mi = 0; mi < 4; ++mi)
                #pragma unroll
                for (int ni = 0; ni < 2; ++ni)
                    acc[mi][ni] = __builtin_amdgcn_mfma_f32_16x16x32_bf16(
                        a[mi], b[ni], acc[mi][ni], 0, 0, 0);
        }
    };

    stage(0, 0);
    __syncthreads();
    #pragma unroll
    for (int t = 0; t < 7; ++t) {
        stage(t + 1, (t + 1) & 1);
        compute(t & 1);
        __syncthreads();
    }
    compute(1);

    #pragma unroll
    for (int mi = 0; mi < 4; ++mi)
        #pragma unroll
        for (int ni = 0; ni < 2; ++ni)
            #pragma unroll
            for (int r = 0; r < 4; ++r)
                out[(size_t)(m0 + wm + mi * 16 + lg * 4 + r) * H_DIM + n0 + wn + ni * 16 + lr] =
                    exp2_fast(LOG2E2 * acc[mi][ni][r]);
}

// ---- phase 1: 32 window scores; multi-acc butterfly reduce (7 shfl / 4 win) ----
// score'(l,w) = sum_h wvn[h] * rcp(1 + Ew[l,h]*Eu[l+j,h])
template<bool EDGE>
__device__ __forceinline__ float score_phase(
    const float* __restrict__ Eu, int l, int lane,
    const float* ewr, const float* wvn)
{
    const float* base = Eu + (size_t)l * H_DIM + lane * 8;
    float sc = 0.0f;
    #pragma unroll
    for (int wg = 0; wg < 8; ++wg) {
        f32x4 u[4][2];
        #pragma unroll
        for (int wi = 0; wi < 4; ++wi) {
            const int w = wg * 4 + wi;
            const int j = (w < P_PAD) ? (w - P_PAD) : (w - P_PAD + 1);
            const float* p;
            if (EDGE) {
                int n = l + j;
                n = min(max(n, 0), L_SEQ - 1);      // clamp; fixed up below
                p = Eu + (size_t)n * H_DIM + lane * 8;
            } else {
                p = base + j * H_DIM;               // compile-time offset
            }
            u[wi][0] = ((const f32x4*)p)[0];
            u[wi][1] = ((const f32x4*)p)[1];
        }
        float a4[4];
        #pragma unroll
        for (int wi = 0; wi < 4; ++wi) {
            float a = 0.0f;
            #pragma unroll
            for (int e = 0; e < 8; ++e) {
                float eu = u[wi][e >> 2][e & 3];
                float q  = __builtin_fmaf(ewr[e], eu, 1.0f);
                a = __builtin_fmaf(wvn[e], __builtin_amdgcn_rcpf(q), a);
            }
            a4[wi] = a;
        }
        // pack 4 accumulators -> lane&3 slots (3 shfl), then 4 butterflies
        const bool b0 = lane & 1, b1 = lane & 2;
        float s01 = b0 ? a4[0] : a4[1];
        float r01 = __shfl_xor(s01, 1);
        float c0  = (b0 ? a4[1] : a4[0]) + r01;     // window wg*4 + b0
        float s23 = b0 ? a4[2] : a4[3];
        float r23 = __shfl_xor(s23, 1);
        float c1  = (b0 ? a4[3] : a4[2]) + r23;     // window wg*4 + 2 + b0
        float s2  = b1 ? c0 : c1;
        float r2  = __shfl_xor(s2, 2);
        float c   = (b1 ? c1 : c0) + r2;            // window wg*4 + (lane&3)
        c += __shfl_xor(c, 4);
        c += __shfl_xor(c, 8);
        c += __shfl_xor(c, 16);
        c += __shfl_xor(c, 32);
        sc = ((lane >> 2) == wg) ? c : sc;
    }

    if (EDGE) {   // OOB windows: score with ux = 0  ->  rcp(1 + Ew)
        float a = 0.0f;
        #pragma unroll
        for (int e = 0; e < 8; ++e)
            a = __builtin_fmaf(wvn[e], __builtin_amdgcn_rcpf(ewr[e] + 1.0f), a);
        #pragma unroll
        for (int off = 32; off; off >>= 1) a += __shfl_xor(a, off);
        const int w = lane & 31;
        const int j = (w < P_PAD) ? (w - P_PAD) : (w - P_PAD + 1);
        const int n = l + j;
        if (n < 0 || n >= L_SEQ) sc = a;
    }
    return sc;
}

__global__ __launch_bounds__(256, 4) void attn_kernel(
    const float* __restrict__ x, const float* __restrict__ Ew,
    const float* __restrict__ Eu, const float* __restrict__ Wv,
    float* __restrict__ g)
{
    // XCD swizzle: grid=1024 -> 128 consecutive blocks per XCD
    const int bid  = (blockIdx.x & 7) * 128 + (blockIdx.x >> 3);
    const int l0   = bid * LB;
    const int tid  = threadIdx.x;
    const int wave = tid >> 6;
    const int lane = tid & 63;
    const int l    = l0 + wave;

    __shared__ float sc_lds[LB][32];
    __shared__ float at_lds[LB][32];

    float ewr[8], wvn[8];
    {
        const f32x4* ewp = (const f32x4*)&Ew[(size_t)l * H_DIM + lane * 8];
        const f32x4* wvp = (const f32x4*)&Wv[lane * 8];
        f32x4 a0 = ewp[0], a1 = ewp[1], v0 = wvp[0], v1 = wvp[1];
        #pragma unroll
        for (int e = 0; e < 4; ++e) {
            ewr[e]     = a0[e];
            ewr[e + 4] = a1[e];
            wvn[e]     = -2.0f * v0[e];
            wvn[e + 4] = -2.0f * v1[e];
        }
    }

    float sc;
    if (l0 >= P_PAD && l0 + LB + P_PAD <= L_SEQ)
        sc = score_phase<false>(Eu, l, lane, ewr, wvn);
    else
        sc = score_phase<true>(Eu, l, lane, ewr, wvn);

    if (lane < 32) sc_lds[wave][lane] = sc;
    __syncthreads();

    // ---- phase 2: softmax over the 32 windows ----
    if (tid < LB * 32) {
        const int ll = tid >> 5, w = tid & 31;
        float s0 = sc_lds[ll][w];
        float m = s0;
        #pragma unroll
        for (int off = 16; off; off >>= 1) m = fmaxf(m, __shfl_xor(m, off, 32));
        float e = exp2_fast((s0 - m) * LOG2E);
        float sum = e;
        #pragma unroll
        for (int off = 16; off; off >>= 1) sum += __shfl_xor(sum, off, 32);
        at_lds[ll][w] = e * __builtin_amdgcn_rcpf(sum);
    }
    __syncthreads();

    // ---- phase 3: g[l][d] = sum_w attn*x[l+j][d]; share 36 x-rows ----
    const int d = tid * 2;
    float2 acc[LB];
    #pragma unroll
    for (int li = 0; li < LB; ++li) acc[li] = make_float2(0.f, 0.f);

    #pragma unroll
    for (int t = 0; t < LB + 2 * P_PAD; ++t) {
        const int n = l0 - P_PAD + t;
        if (n >= 0 && n < L_SEQ) {
            float2 xv = *(const float2*)&x[(size_t)n * D_DIM + d];
            #pragma unroll
            for (int li = 0; li < LB; ++li) {
                const int j = t - P_PAD - li;        // compile-time per (t,li)
                if (j >= -P_PAD && j <= P_PAD && j != 0) {
                    const int w = (j < 0) ? j + P_PAD : j + P_PAD - 1;
                    float a = at_lds[li][w];
                    acc[li].x = __builtin_fmaf(a, xv.x, acc[li].x);
                    acc[li].y = __builtin_fmaf(a, xv.y, acc[li].y);
                }
            }
        }
    }
    #pragma unroll
    for (int li = 0; li < LB; ++li)
        *(float2*)&g[(size_t)(l0 + li) * D_DIM + d] = acc[li];
}

extern "C" void kernel_launch(void* const* d_in, const int* in_sizes, int n_in,
                              void* d_out, int out_size, void* d_ws, size_t ws_size,
                              hipStream_t stream) {
    const float* x  = (const float*)d_in[0];
    const float* Ww = (const float*)d_in[1];
    const float* Wu = (const float*)d_in[2];
    const float* Wv = (const float*)d_in[3];
    float* g = (float*)d_out;

    float*  Ew  = (float*)d_ws;                          // 8 MB f32 [L][H]
    float*  Eu  = Ew + (size_t)L_SEQ * H_DIM;            // 8 MB f32 [L][H]
    ushort* xb  = (ushort*)(Eu + (size_t)L_SEQ * H_DIM); // 4 MB
    ushort* Wwb = xb + (size_t)L_SEQ * D_DIM;            // 0.5 MB
    ushort* Wub = Wwb + (size_t)H_DIM * D_DIM;           // 0.5 MB

    convert_kernel<<<dim3(2560), 256, 0, stream>>>(x, Ww, Wu, xb, Wwb, Wub);
    dual_gemm_mfma<<<dim3(L_SEQ / 128, H_DIM / 64, 2), 256, 0, stream>>>(xb, Wwb, Wub, Ew, Eu);
    attn_kernel<<<dim3(L_SEQ / LB), 256, 0, stream>>>(x, Ew, Eu, Wv, g);
}